// Round 11
// baseline (416.125 us; speedup 1.0000x reference)
//
#include <hip/hip_runtime.h>
#include <hip/hip_fp16.h>
#include <math.h>

#define NN 100000
#define NE 1600000
#define D 64
#define NEG_SLOPE 0.2f
#define NBKT 391          // ceil(NN / 256) buckets of 256 dst nodes
#define NSORT 391         // sort blocks (block b sorts bucket b)
#define NGRID 512         // total blocks in fused kernel (co-resident: cap ~1536)
#define CHUNKF 4096       // edges per sort block (391*4096 >= NE, %4==0)
#define NTILE 1563        // ceil(NN/64) GEMM tiles
#define BCAP 6144         // LDS stage cap per bucket (mean 4096, +6sigma ~4500)

typedef __attribute__((ext_vector_type(8))) short short8;
typedef __attribute__((ext_vector_type(4))) float f32x4;

// ---------------- DPP wave reductions (VALU pipe, no LDS) ----------------
template<int CTRL>
__device__ __forceinline__ float dpp_add(float x) {
    int y = __builtin_amdgcn_update_dpp(0, __float_as_int(x), CTRL, 0xf, 0xf, true);
    return x + __int_as_float(y);
}
template<int CTRL>
__device__ __forceinline__ float dpp_max(float x) {
    int xi = __float_as_int(x);
    int y = __builtin_amdgcn_update_dpp(xi, xi, CTRL, 0xf, 0xf, false);
    return fmaxf(x, __int_as_float(y));
}
__device__ __forceinline__ float wave_sum63(float x) {
    x = dpp_add<0x111>(x); x = dpp_add<0x112>(x); x = dpp_add<0x114>(x);
    x = dpp_add<0x118>(x); x = dpp_add<0x142>(x); x = dpp_add<0x143>(x);
    return x;
}
__device__ __forceinline__ float wave_max63(float x) {
    x = dpp_max<0x111>(x); x = dpp_max<0x112>(x); x = dpp_max<0x114>(x);
    x = dpp_max<0x118>(x); x = dpp_max<0x142>(x); x = dpp_max<0x143>(x);
    return x;
}
__device__ __forceinline__ float rdlane_f(float v, int l) {
    return __int_as_float(__builtin_amdgcn_readlane(__float_as_int(v), l));
}
// RNE float->bf16 bits
__device__ __forceinline__ unsigned bf16_1(float f) {
    unsigned x = __float_as_uint(f);
    return (x + 0x7fffu + ((x >> 16) & 1u)) >> 16;
}
__device__ __forceinline__ unsigned bfpack(float a, float b) {
    return bf16_1(a) | (bf16_1(b) << 16);
}
__device__ __forceinline__ unsigned aload(const unsigned* p) {
    return __hip_atomic_load(p, __ATOMIC_RELAXED, __HIP_MEMORY_SCOPE_AGENT);
}

// =====================================================================
// FUSED: sort pipeline (blocks 0..NSORT-1, 2 ticket barriers) overlapped
// with MFMA GEMM (all blocks, atomic tile stealing).
// =====================================================================
__global__ __launch_bounds__(256) void k_fused(
    const int* __restrict__ src, const int* __restrict__ dst,
    const float* __restrict__ feat, const float* __restrict__ W,
    const float* __restrict__ attn_l, const float* __restrict__ attn_r,
    unsigned* __restrict__ bcnt, unsigned* __restrict__ cur,
    unsigned* __restrict__ ticket1, unsigned* __restrict__ ticket2,
    unsigned* __restrict__ tileCtr,
    unsigned* __restrict__ binned, int* __restrict__ perm,
    unsigned* __restrict__ rowp,
    __half* __restrict__ ft, float* __restrict__ el, float* __restrict__ er)
{
    __shared__ __align__(16) unsigned smem[6660];   // 26,640 B, phase-partitioned
    __shared__ unsigned s_tile;
    int t = threadIdx.x;
    int b = blockIdx.x;

    if (b < NSORT) {
        // ---- phase A1: histogram my chunk into LDS + global bcnt ----
        unsigned* lh = smem;            // [0, 391)
        unsigned* sh = smem + 400;      // [400, 912)
        unsigned b0 = (unsigned)b * CHUNKF;
        unsigned b1 = min(b0 + CHUNKF, (unsigned)NE);
        unsigned n4 = (b1 - b0) >> 2;
        for (int k = t; k < NBKT; k += 256) lh[k] = 0u;
        __syncthreads();
        const int4* d4 = (const int4*)(dst + b0);
        const int4* s4 = (const int4*)(src + b0);
        for (unsigned i = t; i < n4; i += 256) {
            int4 v = d4[i];
            atomicAdd(&lh[((unsigned)v.x) >> 8], 1u);
            atomicAdd(&lh[((unsigned)v.y) >> 8], 1u);
            atomicAdd(&lh[((unsigned)v.z) >> 8], 1u);
            atomicAdd(&lh[((unsigned)v.w) >> 8], 1u);
        }
        __syncthreads();
        for (int k = t; k < NBKT; k += 256)
            if (lh[k]) atomicAdd(&bcnt[k], lh[k]);
        // ---- barrier 1 (all sort blocks' bcnt adds visible) ----
        __threadfence();
        __syncthreads();
        if (t == 0) {
            atomicAdd(ticket1, 1u);
            while (__hip_atomic_load(ticket1, __ATOMIC_ACQUIRE,
                                     __HIP_MEMORY_SCOPE_AGENT) < (unsigned)NSORT)
                __builtin_amdgcn_s_sleep(8);
        }
        __syncthreads();
        __threadfence();
        // ---- phase A2: local inclusive scan of bcnt (512-wide, 2/thread) ----
        sh[t]       = (t < NBKT)       ? aload(&bcnt[t])       : 0u;
        sh[t + 256] = (t + 256 < NBKT) ? aload(&bcnt[t + 256]) : 0u;
        __syncthreads();
        for (int off = 1; off < 512; off <<= 1) {
            unsigned u0 = (t >= off) ? sh[t - off] : 0u;
            unsigned u1 = (t + 256 >= off) ? sh[t + 256 - off] : 0u;
            __syncthreads();
            sh[t] += u0;
            sh[t + 256] += u1;
            __syncthreads();
        }
        unsigned myBeg = b ? sh[b - 1] : 0u;    // my bucket range for phase B
        unsigned myEnd = sh[b];
        // reserve contiguous runs per bucket for my chunk
        for (int k = t; k < NBKT; k += 256) {
            unsigned c = lh[k];
            if (c) {
                unsigned base = k ? sh[k - 1] : 0u;
                lh[k] = base + atomicAdd(&cur[k], c);
            }
        }
        __syncthreads();
        // scatter my chunk into bucket-contiguous binned (packed src<<8|dloc)
        for (unsigned i = t; i < n4; i += 256) {
            int4 dv = d4[i];
            int4 sv = s4[i];
            { unsigned d_=(unsigned)dv.x, s_=(unsigned)sv.x;
              unsigned pos=atomicAdd(&lh[d_>>8],1u); binned[pos]=(s_<<8)|(d_&255u); }
            { unsigned d_=(unsigned)dv.y, s_=(unsigned)sv.y;
              unsigned pos=atomicAdd(&lh[d_>>8],1u); binned[pos]=(s_<<8)|(d_&255u); }
            { unsigned d_=(unsigned)dv.z, s_=(unsigned)sv.z;
              unsigned pos=atomicAdd(&lh[d_>>8],1u); binned[pos]=(s_<<8)|(d_&255u); }
            { unsigned d_=(unsigned)dv.w, s_=(unsigned)sv.w;
              unsigned pos=atomicAdd(&lh[d_>>8],1u); binned[pos]=(s_<<8)|(d_&255u); }
        }
        // ---- barrier 2 (all binned writes visible) ----
        __threadfence();
        __syncthreads();
        if (t == 0) {
            atomicAdd(ticket2, 1u);
            while (__hip_atomic_load(ticket2, __ATOMIC_ACQUIRE,
                                     __HIP_MEMORY_SCOPE_AGENT) < (unsigned)NSORT)
                __builtin_amdgcn_s_sleep(8);
        }
        __syncthreads();
        __threadfence();
        // ---- phase B: counting-sort bucket b -> perm + rowp ----
        unsigned* lh2   = smem;         // 256 counters
        unsigned* cur2  = smem + 256;   // 256 cursors
        unsigned* stage = smem + 512;   // BCAP entries
        unsigned cnt = myEnd - myBeg;
        lh2[t] = 0u;
        __syncthreads();
        if (cnt <= BCAP) {
            for (unsigned i = t; i < cnt; i += 256) {
                unsigned wv = aload(&binned[myBeg + i]);
                stage[i] = wv;
                atomicAdd(&lh2[wv & 255u], 1u);
            }
        } else {
            for (unsigned i = myBeg + t; i < myEnd; i += 256)
                atomicAdd(&lh2[aload(&binned[i]) & 255u], 1u);
        }
        __syncthreads();
        for (int off = 1; off < 256; off <<= 1) {
            unsigned u = (t >= off) ? lh2[t - off] : 0u;
            __syncthreads();
            lh2[t] += u;
            __syncthreads();
        }
        unsigned start = (t == 0) ? 0u : lh2[t - 1];
        unsigned node = ((unsigned)b << 8) + (unsigned)t;
        if (node <= NN) rowp[node] = myBeg + start;   // last bucket writes rowp[NN]=NE
        cur2[t] = start;
        __syncthreads();
        if (cnt <= BCAP) {
            for (unsigned i = t; i < cnt; i += 256) {
                unsigned wv = stage[i];
                unsigned pos = atomicAdd(&cur2[wv & 255u], 1u);
                perm[myBeg + pos] = (int)(wv >> 8);
            }
        } else {
            for (unsigned i = myBeg + t; i < myEnd; i += 256) {
                unsigned wv = aload(&binned[i]);
                unsigned pos = atomicAdd(&cur2[wv & 255u], 1u);
                perm[myBeg + pos] = (int)(wv >> 8);
            }
        }
        __syncthreads();
    }

    // ---- GEMM phase: all blocks steal tiles (GEMM-only blocks start at t=0) ----
    unsigned short* Ab = (unsigned short*)smem;            // 8 KB
    unsigned short* Bb = (unsigned short*)(smem + 2048);   // 8 KB
    float* wlS = (float*)(smem + 4096);                    // 64 f
    float* wrS = (float*)(smem + 4160);                    // 64 f
    // build wl/wr + swizzled bf16 W^T once per block
    {
        int k = t >> 2, s = t & 3;
        float pl = 0.f, pr = 0.f;
        #pragma unroll
        for (int q = 0; q < 4; ++q) {
            int seg = s + q * 4;
            float4 f = *(const float4*)(W + k * 64 + seg * 4);
            float4 a = *(const float4*)(attn_l + seg * 4);
            float4 bb = *(const float4*)(attn_r + seg * 4);
            pl += f.x*a.x + f.y*a.y + f.z*a.z + f.w*a.w;
            pr += f.x*bb.x + f.y*bb.y + f.z*bb.z + f.w*bb.w;
        }
        pl += __shfl_xor(pl, 1, 64); pl += __shfl_xor(pl, 2, 64);
        pr += __shfl_xor(pr, 1, 64); pr += __shfl_xor(pr, 2, 64);
        if (s == 0) { wlS[k] = pl; wrS[k] = pr; }
    }
    {
        int j = t & 63, g = t >> 6;
        unsigned m = (unsigned)((j & 7) << 4);
        #pragma unroll
        for (int i = 0; i < 8; ++i) {
            int k0 = g * 16 + i * 2;
            float w0 = W[k0 * 64 + j];
            float w1 = W[(k0 + 1) * 64 + j];
            *(unsigned*)((char*)Bb + j * 128 + (((unsigned)(k0 * 2)) ^ m)) = bfpack(w0, w1);
        }
    }
    __syncthreads();

    int w = t >> 6, l = t & 63;
    int lr = l & 15, lg = l >> 4;
    while (true) {
        if (t == 0) s_tile = atomicAdd(tileCtr, 1u);
        __syncthreads();
        unsigned tile = s_tile;
        if (tile >= (unsigned)NTILE) break;
        int n0 = (int)tile * 64;
        // stage feat tile -> Ab (bf16, swizzled) + exact fp32 el/er
        {
            int r = t >> 2, s = t & 3;
            int n = n0 + r;
            bool valid = n < NN;
            const float* fp = feat + (size_t)(valid ? n : (NN - 1)) * D;
            float pl = 0.f, pr = 0.f;
            unsigned m = (unsigned)((r & 7) << 4);
            #pragma unroll
            for (int q = 0; q < 4; ++q) {
                int seg = s + q * 4;
                float4 f = *(const float4*)(fp + seg * 4);
                float4 a = *(const float4*)(wlS + seg * 4);
                float4 bb = *(const float4*)(wrS + seg * 4);
                pl += f.x*a.x + f.y*a.y + f.z*a.z + f.w*a.w;
                pr += f.x*bb.x + f.y*bb.y + f.z*bb.z + f.w*bb.w;
                uint2 pk;
                pk.x = bfpack(f.x, f.y);
                pk.y = bfpack(f.z, f.w);
                *(uint2*)((char*)Ab + r * 128 + (((unsigned)(seg * 8)) ^ m)) = pk;
            }
            pl += __shfl_xor(pl, 1, 64); pl += __shfl_xor(pl, 2, 64);
            pr += __shfl_xor(pr, 1, 64); pr += __shfl_xor(pr, 2, 64);
            if (s == 0 && valid) { el[n] = pl; er[n] = pr; }
        }
        __syncthreads();
        // MFMA: wave w -> cols 16w..16w+15
        f32x4 acc0 = {0.f,0.f,0.f,0.f};
        f32x4 acc1 = {0.f,0.f,0.f,0.f};
        f32x4 acc2 = {0.f,0.f,0.f,0.f};
        f32x4 acc3 = {0.f,0.f,0.f,0.f};
        int jrow = w * 16 + lr;
        unsigned bm = (unsigned)((jrow & 7) << 4);
        short8 bf0 = *(const short8*)((char*)Bb + jrow * 128 + (((unsigned)(0 + lg * 16)) ^ bm));
        short8 bf1 = *(const short8*)((char*)Bb + jrow * 128 + (((unsigned)(64 + lg * 16)) ^ bm));
        #pragma unroll
        for (int rt = 0; rt < 4; ++rt) {
            int arow = rt * 16 + lr;
            unsigned am = (unsigned)((arow & 7) << 4);
            short8 a0 = *(const short8*)((char*)Ab + arow * 128 + (((unsigned)(0 + lg * 16)) ^ am));
            short8 a1 = *(const short8*)((char*)Ab + arow * 128 + (((unsigned)(64 + lg * 16)) ^ am));
            f32x4 acc = (rt == 0) ? acc0 : (rt == 1) ? acc1 : (rt == 2) ? acc2 : acc3;
            acc = __builtin_amdgcn_mfma_f32_16x16x32_bf16(a0, bf0, acc, 0, 0, 0);
            acc = __builtin_amdgcn_mfma_f32_16x16x32_bf16(a1, bf1, acc, 0, 0, 0);
            if (rt == 0) acc0 = acc; else if (rt == 1) acc1 = acc;
            else if (rt == 2) acc2 = acc; else acc3 = acc;
        }
        int col = w * 16 + lr;
        #pragma unroll
        for (int rt = 0; rt < 4; ++rt) {
            f32x4 acc = (rt == 0) ? acc0 : (rt == 1) ? acc1 : (rt == 2) ? acc2 : acc3;
            #pragma unroll
            for (int i = 0; i < 4; ++i) {
                int row = rt * 16 + lg * 4 + i;
                int nn = n0 + row;
                if (nn < NN) ft[(size_t)nn * D + col] = __float2half(acc[i]);
            }
        }
        __syncthreads();   // Ab reads done before next tile's staging
    }
}

// ---- fallback: full-wave processing of one node (deg > 64) ----
__device__ __noinline__ void agg_node64(int d, int lane,
                                        const unsigned* __restrict__ row,
                                        const int* __restrict__ perm_src,
                                        const float* __restrict__ el,
                                        const float* __restrict__ er,
                                        const __half* __restrict__ ft,
                                        const float* __restrict__ feat,
                                        const float* __restrict__ bias,
                                        float* __restrict__ out) {
    unsigned beg = row[d], end = row[d + 1];
    float er_d = er[d];
    float acc = 0.0f;
    float s = 0.0f;
    float m = -INFINITY;
    for (unsigned base = beg; base < end; base += 64) {
        unsigned i = base + lane;
        float e = -INFINITY;
        if (i < end) {
            int sid2 = perm_src[i];
            float v = el[sid2] + er_d;
            e = v > 0.0f ? v : NEG_SLOPE * v;
        }
        m = fmaxf(m, rdlane_f(wave_max63(e), 63));
    }
    for (unsigned base = beg; base < end; base += 64) {
        unsigned i = base + lane;
        float exx = 0.0f;
        if (i < end) {
            int sid2 = perm_src[i];
            float v = el[sid2] + er_d;
            v = v > 0.0f ? v : NEG_SLOPE * v;
            exx = __expf(v - m);
        }
        s += rdlane_f(wave_sum63(exx), 63);
    }
    for (unsigned jj = beg; jj < end; ++jj) {
        int sj = perm_src[jj];
        float v = el[sj] + er_d;
        v = v > 0.0f ? v : NEG_SLOPE * v;
        acc = fmaf(__half2float(ft[((size_t)sj << 6) + lane]), __expf(v - m), acc);
    }
    acc /= s;
    out[(size_t)d * D + lane] = acc + feat[(size_t)d * D + lane] + bias[lane];
}

// 32-bit byte-offset gather: base SGPR + (sid<<7 | lane<<1)
#define LOAD8(B, J) do { \
    unsigned _o0 = (((unsigned)__builtin_amdgcn_readlane(sid, (J) + 0)) << 7) | lb; \
    unsigned _o1 = (((unsigned)__builtin_amdgcn_readlane(sid, (J) + 1)) << 7) | lb; \
    unsigned _o2 = (((unsigned)__builtin_amdgcn_readlane(sid, (J) + 2)) << 7) | lb; \
    unsigned _o3 = (((unsigned)__builtin_amdgcn_readlane(sid, (J) + 3)) << 7) | lb; \
    unsigned _o4 = (((unsigned)__builtin_amdgcn_readlane(sid, (J) + 4)) << 7) | lb; \
    unsigned _o5 = (((unsigned)__builtin_amdgcn_readlane(sid, (J) + 5)) << 7) | lb; \
    unsigned _o6 = (((unsigned)__builtin_amdgcn_readlane(sid, (J) + 6)) << 7) | lb; \
    unsigned _o7 = (((unsigned)__builtin_amdgcn_readlane(sid, (J) + 7)) << 7) | lb; \
    B##0 = *(const __half*)(ftb + _o0); \
    B##1 = *(const __half*)(ftb + _o1); \
    B##2 = *(const __half*)(ftb + _o2); \
    B##3 = *(const __half*)(ftb + _o3); \
    B##4 = *(const __half*)(ftb + _o4); \
    B##5 = *(const __half*)(ftb + _o5); \
    B##6 = *(const __half*)(ftb + _o6); \
    B##7 = *(const __half*)(ftb + _o7); \
} while (0)

#define FMA8(B, J) do { \
    acc = fmaf(__half2float(B##0), rdlane_f(ex, (J) + 0), acc); \
    acc = fmaf(__half2float(B##1), rdlane_f(ex, (J) + 1), acc); \
    acc = fmaf(__half2float(B##2), rdlane_f(ex, (J) + 2), acc); \
    acc = fmaf(__half2float(B##3), rdlane_f(ex, (J) + 3), acc); \
    acc = fmaf(__half2float(B##4), rdlane_f(ex, (J) + 4), acc); \
    acc = fmaf(__half2float(B##5), rdlane_f(ex, (J) + 5), acc); \
    acc = fmaf(__half2float(B##6), rdlane_f(ex, (J) + 6), acc); \
    acc = fmaf(__half2float(B##7), rdlane_f(ex, (J) + 7), acc); \
} while (0)

// fused edge-softmax + aggregation, one wave per node, software-pipelined.
__global__ __launch_bounds__(256) void k_agg(const unsigned* __restrict__ row,
                                             const int* __restrict__ perm_src,
                                             const float* __restrict__ el,
                                             const float* __restrict__ er,
                                             const __half* __restrict__ ft,
                                             const float* __restrict__ feat,
                                             const float* __restrict__ bias,
                                             float* __restrict__ out) {
    int gid = blockIdx.x * 256 + threadIdx.x;
    int d = gid >> 6;
    int lane = gid & 63;
    if (d >= NN) return;

    unsigned beg = row[d], end = row[d + 1];
    int deg = (int)(end - beg);

    if (deg > 64) {
        agg_node64(d, lane, row, perm_src, el, er, ft, feat, bias, out);
        return;
    }
    if (deg == 0) {
        out[(size_t)d * D + lane] = feat[(size_t)d * D + lane] + bias[lane];
        return;
    }

    float er_d = er[d];
    int sid = perm_src[beg + ((lane < deg) ? lane : 0)];
    float elv = el[sid];                      // issued early

    const char* ftb = (const char*)ft;
    unsigned lb = (unsigned)lane << 1;

    __half c0, c1, c2, c3, c4, c5, c6, c7;
    __half n0, n1, n2, n3, n4, n5, n6, n7;
    LOAD8(c, 0);                              // batch 0 in flight during softmax

    float e = elv + er_d;
    e = e > 0.0f ? e : NEG_SLOPE * e;
    float ex = (lane < deg) ? __expf(e) : 0.0f;   // no max-subtract (bounded e)
    float s = rdlane_f(wave_sum63(ex), 63);
    float inv_s = __frcp_rn(s);

    float acc = 0.0f;
    int j = 0;
    while (true) {
        bool more = (j + 8) < deg;
        if (more) LOAD8(n, j + 8);
        FMA8(c, j);
        j += 8;
        if (!more) break;
        bool more2 = (j + 8) < deg;
        if (more2) LOAD8(c, j + 8);
        FMA8(n, j);
        j += 8;
        if (!more2) break;
    }
    acc *= inv_s;
    out[(size_t)d * D + lane] = acc + feat[(size_t)d * D + lane] + bias[lane];
}

extern "C" void kernel_launch(void* const* d_in, const int* in_sizes, int n_in,
                              void* d_out, int out_size, void* d_ws, size_t ws_size,
                              hipStream_t stream) {
    const float* feat   = (const float*)d_in[0];
    const float* W      = (const float*)d_in[1];
    const float* attn_l = (const float*)d_in[2];
    const float* attn_r = (const float*)d_in[3];
    const float* bias   = (const float*)d_in[4];
    const int*   src    = (const int*)d_in[5];
    const int*   dst    = (const int*)d_in[6];
    float* out = (float*)d_out;

    char* ws = (char*)d_ws;
    __half*   ft     = (__half*)(ws);                // [0, 12,800,000)
    float*    el     = (float*)(ws + 12800000);      // 400,000
    float*    er     = (float*)(ws + 13200000);      // 400,000
    int*      perm   = (int*)(ws + 13600000);        // 6,400,000 -> 20,000,000
    unsigned* rowp   = (unsigned*)(ws + 20000000);   // 400,004
    unsigned* binned = (unsigned*)(ws + 20400128);   // 6,400,000 -> 26,800,128
    unsigned* ctrs   = (unsigned*)(ws + 26800128);   // counters block
    unsigned* bcnt    = ctrs;          // 391
    unsigned* cur     = ctrs + 400;    // 391
    unsigned* ticket1 = ctrs + 800;
    unsigned* ticket2 = ctrs + 801;
    unsigned* tileCtr = ctrs + 802;

    hipMemsetAsync(ctrs, 0, 804 * sizeof(unsigned), stream);
    k_fused<<<NGRID, 256, 0, stream>>>(src, dst, feat, W, attn_l, attn_r,
                                       bcnt, cur, ticket1, ticket2, tileCtr,
                                       binned, perm, rowp, ft, el, er);
    k_agg<<<(NN * 64 + 255) / 256, 256, 0, stream>>>(rowp, perm, el, er,
                                                     ft, feat, bias, out);
}

// Round 12
// 101.683 us; speedup vs baseline: 4.0924x; 4.0924x over previous
//
#include <hip/hip_runtime.h>
#include <hip/hip_fp16.h>
#include <math.h>

#define NN 100000
#define NE 1600000
#define D 64
#define NEG_SLOPE 0.2f
#define NBKT 391          // ceil(NN/256) buckets of 256 dst nodes
#define NB1 196           // streaming blocks for k_bin
#define CHUNK 8192        // edges per streaming block (%4==0)
#define BSLOT 5120        // slots per bucket (mean 4096, sd 64 -> +16 sigma)

typedef __attribute__((ext_vector_type(8))) short short8;
typedef __attribute__((ext_vector_type(4))) float f32x4;

// ---------------- DPP wave reductions (VALU pipe, no LDS) ----------------
template<int CTRL>
__device__ __forceinline__ float dpp_add(float x) {
    int y = __builtin_amdgcn_update_dpp(0, __float_as_int(x), CTRL, 0xf, 0xf, true);
    return x + __int_as_float(y);
}
template<int CTRL>
__device__ __forceinline__ float dpp_max(float x) {
    int xi = __float_as_int(x);
    int y = __builtin_amdgcn_update_dpp(xi, xi, CTRL, 0xf, 0xf, false);
    return fmaxf(x, __int_as_float(y));
}
__device__ __forceinline__ float wave_sum63(float x) {
    x = dpp_add<0x111>(x); x = dpp_add<0x112>(x); x = dpp_add<0x114>(x);
    x = dpp_add<0x118>(x); x = dpp_add<0x142>(x); x = dpp_add<0x143>(x);
    return x;
}
__device__ __forceinline__ float wave_max63(float x) {
    x = dpp_max<0x111>(x); x = dpp_max<0x112>(x); x = dpp_max<0x114>(x);
    x = dpp_max<0x118>(x); x = dpp_max<0x142>(x); x = dpp_max<0x143>(x);
    return x;
}
__device__ __forceinline__ float rdlane_f(float v, int l) {
    return __int_as_float(__builtin_amdgcn_readlane(__float_as_int(v), l));
}
// RNE float->bf16 bits
__device__ __forceinline__ unsigned bf16_1(float f) {
    unsigned x = __float_as_uint(f);
    return (x + 0x7fffu + ((x >> 16) & 1u)) >> 16;
}
__device__ __forceinline__ unsigned bfpack(float a, float b) {
    return bf16_1(a) | (bf16_1(b) << 16);
}

// ---- k_bin: histogram + self-reserve (slotted buckets) + scatter ----
__global__ __launch_bounds__(256) void k_bin(const int* __restrict__ src,
                                             const int* __restrict__ dst,
                                             unsigned* __restrict__ bcnt,
                                             unsigned* __restrict__ binned) {
    __shared__ unsigned lh[NBKT];
    int t = threadIdx.x;
    unsigned b0 = blockIdx.x * CHUNK;
    unsigned b1 = min(b0 + CHUNK, (unsigned)NE);
    unsigned n4 = (b1 - b0) >> 2;
    for (int k = t; k < NBKT; k += 256) lh[k] = 0u;
    __syncthreads();
    const int4* d4 = (const int4*)(dst + b0);
    const int4* s4 = (const int4*)(src + b0);
    for (unsigned i = t; i < n4; i += 256) {
        int4 v = d4[i];
        atomicAdd(&lh[((unsigned)v.x) >> 8], 1u);
        atomicAdd(&lh[((unsigned)v.y) >> 8], 1u);
        atomicAdd(&lh[((unsigned)v.z) >> 8], 1u);
        atomicAdd(&lh[((unsigned)v.w) >> 8], 1u);
    }
    __syncthreads();
    // reserve a contiguous run inside the bucket's fixed slot region
    for (int k = t; k < NBKT; k += 256) {
        unsigned c = lh[k];
        if (c) lh[k] = (unsigned)k * BSLOT + atomicAdd(&bcnt[k], c);
    }
    __syncthreads();
    for (unsigned i = t; i < n4; i += 256) {
        int4 dv = d4[i];
        int4 sv = s4[i];
        { unsigned d_=(unsigned)dv.x, s_=(unsigned)sv.x;
          unsigned pos=atomicAdd(&lh[d_>>8],1u); binned[pos]=(s_<<8)|(d_&255u); }
        { unsigned d_=(unsigned)dv.y, s_=(unsigned)sv.y;
          unsigned pos=atomicAdd(&lh[d_>>8],1u); binned[pos]=(s_<<8)|(d_&255u); }
        { unsigned d_=(unsigned)dv.z, s_=(unsigned)sv.z;
          unsigned pos=atomicAdd(&lh[d_>>8],1u); binned[pos]=(s_<<8)|(d_&255u); }
        { unsigned d_=(unsigned)dv.w, s_=(unsigned)sv.w;
          unsigned pos=atomicAdd(&lh[d_>>8],1u); binned[pos]=(s_<<8)|(d_&255u); }
    }
}

// ---- k_bsort: per-bucket counting sort; emits per-node (beg,end) ----
__global__ __launch_bounds__(256) void k_bsort(const unsigned* __restrict__ bcnt,
                                               const unsigned* __restrict__ binned,
                                               int* __restrict__ perm,
                                               uint2* __restrict__ rowBE) {
    __shared__ unsigned lh[256];
    __shared__ unsigned cur[256];
    __shared__ unsigned stage[BSLOT];
    int t = threadIdx.x;
    int b = blockIdx.x;
    unsigned beg = (unsigned)b * BSLOT;
    unsigned cnt = bcnt[b];
    lh[t] = 0u;
    __syncthreads();
    for (unsigned i = t; i < cnt; i += 256) {
        unsigned w = binned[beg + i];
        stage[i] = w;
        atomicAdd(&lh[w & 255u], 1u);
    }
    __syncthreads();
    for (int off = 1; off < 256; off <<= 1) {     // inclusive scan
        unsigned u = (t >= off) ? lh[t - off] : 0u;
        __syncthreads();
        lh[t] += u;
        __syncthreads();
    }
    unsigned start = (t == 0) ? 0u : lh[t - 1];
    unsigned node = ((unsigned)b << 8) + (unsigned)t;
    if (node < NN) {
        uint2 be; be.x = beg + start; be.y = beg + lh[t];
        rowBE[node] = be;
    }
    cur[t] = start;
    __syncthreads();
    for (unsigned i = t; i < cnt; i += 256) {
        unsigned w = stage[i];
        unsigned pos = atomicAdd(&cur[w & 255u], 1u);
        perm[beg + pos] = (int)(w >> 8);
    }
}

// ---- MFMA GEMM with fused weight prep (proven R10 structure) ----
__global__ __launch_bounds__(256) void k1_mfma(const float* __restrict__ feat,
                                               const float* __restrict__ W,
                                               const float* __restrict__ attn_l,
                                               const float* __restrict__ attn_r,
                                               __half* __restrict__ ft,
                                               float* __restrict__ el,
                                               float* __restrict__ er) {
    __shared__ unsigned short Ab[64 * 64];
    __shared__ unsigned short Bb[64 * 64];
    __shared__ float wlS[64], wrS[64];
    int t = threadIdx.x;
    int n0 = blockIdx.x * 64;

    {
        int k = t >> 2, s = t & 3;
        float pl = 0.f, pr = 0.f;
        #pragma unroll
        for (int q = 0; q < 4; ++q) {
            int seg = s + q * 4;
            float4 f = *(const float4*)(W + k * 64 + seg * 4);
            float4 a = *(const float4*)(attn_l + seg * 4);
            float4 b = *(const float4*)(attn_r + seg * 4);
            pl += f.x*a.x + f.y*a.y + f.z*a.z + f.w*a.w;
            pr += f.x*b.x + f.y*b.y + f.z*b.z + f.w*b.w;
        }
        pl += __shfl_xor(pl, 1, 64); pl += __shfl_xor(pl, 2, 64);
        pr += __shfl_xor(pr, 1, 64); pr += __shfl_xor(pr, 2, 64);
        if (s == 0) { wlS[k] = pl; wrS[k] = pr; }
    }
    {
        int j = t & 63, g = t >> 6;
        unsigned m = (unsigned)((j & 7) << 4);
        #pragma unroll
        for (int i = 0; i < 8; ++i) {
            int k0 = g * 16 + i * 2;
            float w0 = W[k0 * 64 + j];
            float w1 = W[(k0 + 1) * 64 + j];
            *(unsigned*)((char*)Bb + j * 128 + (((unsigned)(k0 * 2)) ^ m)) = bfpack(w0, w1);
        }
    }
    __syncthreads();
    {
        int r = t >> 2, s = t & 3;
        int n = n0 + r;
        bool valid = n < NN;
        const float* fp = feat + (size_t)(valid ? n : (NN - 1)) * D;
        float pl = 0.f, pr = 0.f;
        unsigned m = (unsigned)((r & 7) << 4);
        #pragma unroll
        for (int q = 0; q < 4; ++q) {
            int seg = s + q * 4;
            float4 f = *(const float4*)(fp + seg * 4);
            float4 a = *(const float4*)(wlS + seg * 4);
            float4 b = *(const float4*)(wrS + seg * 4);
            pl += f.x*a.x + f.y*a.y + f.z*a.z + f.w*a.w;
            pr += f.x*b.x + f.y*b.y + f.z*b.z + f.w*b.w;
            uint2 pk;
            pk.x = bfpack(f.x, f.y);
            pk.y = bfpack(f.z, f.w);
            *(uint2*)((char*)Ab + r * 128 + (((unsigned)(seg * 8)) ^ m)) = pk;
        }
        pl += __shfl_xor(pl, 1, 64); pl += __shfl_xor(pl, 2, 64);
        pr += __shfl_xor(pr, 1, 64); pr += __shfl_xor(pr, 2, 64);
        if (s == 0 && valid) { el[n] = pl; er[n] = pr; }
    }
    __syncthreads();

    int w = t >> 6, l = t & 63;
    int lr = l & 15, lg = l >> 4;
    f32x4 acc0 = {0.f,0.f,0.f,0.f};
    f32x4 acc1 = {0.f,0.f,0.f,0.f};
    f32x4 acc2 = {0.f,0.f,0.f,0.f};
    f32x4 acc3 = {0.f,0.f,0.f,0.f};

    int jrow = w * 16 + lr;
    unsigned bm = (unsigned)((jrow & 7) << 4);
    short8 bf0 = *(const short8*)((char*)Bb + jrow * 128 + (((unsigned)(0 + lg * 16)) ^ bm));
    short8 bf1 = *(const short8*)((char*)Bb + jrow * 128 + (((unsigned)(64 + lg * 16)) ^ bm));

    #pragma unroll
    for (int rt = 0; rt < 4; ++rt) {
        int arow = rt * 16 + lr;
        unsigned am = (unsigned)((arow & 7) << 4);
        short8 a0 = *(const short8*)((char*)Ab + arow * 128 + (((unsigned)(0 + lg * 16)) ^ am));
        short8 a1 = *(const short8*)((char*)Ab + arow * 128 + (((unsigned)(64 + lg * 16)) ^ am));
        f32x4 acc = (rt == 0) ? acc0 : (rt == 1) ? acc1 : (rt == 2) ? acc2 : acc3;
        acc = __builtin_amdgcn_mfma_f32_16x16x32_bf16(a0, bf0, acc, 0, 0, 0);
        acc = __builtin_amdgcn_mfma_f32_16x16x32_bf16(a1, bf1, acc, 0, 0, 0);
        if (rt == 0) acc0 = acc; else if (rt == 1) acc1 = acc;
        else if (rt == 2) acc2 = acc; else acc3 = acc;
    }

    int col = w * 16 + lr;
    #pragma unroll
    for (int rt = 0; rt < 4; ++rt) {
        f32x4 acc = (rt == 0) ? acc0 : (rt == 1) ? acc1 : (rt == 2) ? acc2 : acc3;
        #pragma unroll
        for (int i = 0; i < 4; ++i) {
            int row = rt * 16 + lg * 4 + i;
            int nn = n0 + row;
            if (nn < NN) ft[(size_t)nn * D + col] = __float2half(acc[i]);
        }
    }
}

// ---- fallback: full-wave processing of one node (deg > 64) ----
__device__ __noinline__ void agg_node64(int d, int lane, unsigned beg, unsigned end,
                                        const int* __restrict__ perm_src,
                                        const float* __restrict__ el, float er_d,
                                        const __half* __restrict__ ft,
                                        const float* __restrict__ feat,
                                        const float* __restrict__ bias,
                                        float* __restrict__ out) {
    float acc = 0.0f;
    float s = 0.0f;
    float m = -INFINITY;
    for (unsigned base = beg; base < end; base += 64) {
        unsigned i = base + lane;
        float e = -INFINITY;
        if (i < end) {
            int sid2 = perm_src[i];
            float v = el[sid2] + er_d;
            e = v > 0.0f ? v : NEG_SLOPE * v;
        }
        m = fmaxf(m, rdlane_f(wave_max63(e), 63));
    }
    for (unsigned base = beg; base < end; base += 64) {
        unsigned i = base + lane;
        float exx = 0.0f;
        if (i < end) {
            int sid2 = perm_src[i];
            float v = el[sid2] + er_d;
            v = v > 0.0f ? v : NEG_SLOPE * v;
            exx = __expf(v - m);
        }
        s += rdlane_f(wave_sum63(exx), 63);
    }
    for (unsigned jj = beg; jj < end; ++jj) {
        int sj = perm_src[jj];
        float v = el[sj] + er_d;
        v = v > 0.0f ? v : NEG_SLOPE * v;
        acc = fmaf(__half2float(ft[((size_t)sj << 6) + lane]), __expf(v - m), acc);
    }
    acc /= s;
    out[(size_t)d * D + lane] = acc + feat[(size_t)d * D + lane] + bias[lane];
}

// uniform-base gather: SGPR pointer = ftb + (sid<<7); voffset = lane*2
#define LOAD8(B, J) do { \
    const __half* _p0 = (const __half*)(ftb + (((unsigned)__builtin_amdgcn_readlane(sid, (J) + 0)) << 7)); \
    const __half* _p1 = (const __half*)(ftb + (((unsigned)__builtin_amdgcn_readlane(sid, (J) + 1)) << 7)); \
    const __half* _p2 = (const __half*)(ftb + (((unsigned)__builtin_amdgcn_readlane(sid, (J) + 2)) << 7)); \
    const __half* _p3 = (const __half*)(ftb + (((unsigned)__builtin_amdgcn_readlane(sid, (J) + 3)) << 7)); \
    const __half* _p4 = (const __half*)(ftb + (((unsigned)__builtin_amdgcn_readlane(sid, (J) + 4)) << 7)); \
    const __half* _p5 = (const __half*)(ftb + (((unsigned)__builtin_amdgcn_readlane(sid, (J) + 5)) << 7)); \
    const __half* _p6 = (const __half*)(ftb + (((unsigned)__builtin_amdgcn_readlane(sid, (J) + 6)) << 7)); \
    const __half* _p7 = (const __half*)(ftb + (((unsigned)__builtin_amdgcn_readlane(sid, (J) + 7)) << 7)); \
    B##0 = _p0[lane]; B##1 = _p1[lane]; B##2 = _p2[lane]; B##3 = _p3[lane]; \
    B##4 = _p4[lane]; B##5 = _p5[lane]; B##6 = _p6[lane]; B##7 = _p7[lane]; \
} while (0)

#define FMA8(B, J) do { \
    acc = fmaf(__half2float(B##0), rdlane_f(ex, (J) + 0), acc); \
    acc = fmaf(__half2float(B##1), rdlane_f(ex, (J) + 1), acc); \
    acc = fmaf(__half2float(B##2), rdlane_f(ex, (J) + 2), acc); \
    acc = fmaf(__half2float(B##3), rdlane_f(ex, (J) + 3), acc); \
    acc = fmaf(__half2float(B##4), rdlane_f(ex, (J) + 4), acc); \
    acc = fmaf(__half2float(B##5), rdlane_f(ex, (J) + 5), acc); \
    acc = fmaf(__half2float(B##6), rdlane_f(ex, (J) + 6), acc); \
    acc = fmaf(__half2float(B##7), rdlane_f(ex, (J) + 7), acc); \
} while (0)

// fused edge-softmax + aggregation, one wave per node, software-pipelined.
__global__ __launch_bounds__(256) void k_agg(const uint2* __restrict__ rowBE,
                                             const int* __restrict__ perm_src,
                                             const float* __restrict__ el,
                                             const float* __restrict__ er,
                                             const __half* __restrict__ ft,
                                             const float* __restrict__ feat,
                                             const float* __restrict__ bias,
                                             float* __restrict__ out) {
    int gid = blockIdx.x * 256 + threadIdx.x;
    int d = gid >> 6;
    int lane = gid & 63;
    if (d >= NN) return;

    uint2 be = rowBE[d];
    unsigned beg = be.x;
    int deg = (int)(be.y - be.x);
    float er_d = er[d];

    if (deg > 64) {
        agg_node64(d, lane, be.x, be.y, perm_src, el, er_d, ft, feat, bias, out);
        return;
    }
    if (deg == 0) {
        out[(size_t)d * D + lane] = feat[(size_t)d * D + lane] + bias[lane];
        return;
    }

    int sid = perm_src[beg + ((lane < deg) ? lane : 0)];
    float elv = el[sid];                      // issued early

    const char* ftb = (const char*)ft;

    __half c0, c1, c2, c3, c4, c5, c6, c7;
    __half n0, n1, n2, n3, n4, n5, n6, n7;
    LOAD8(c, 0);                              // batch 0 in flight during softmax

    float e = elv + er_d;
    e = e > 0.0f ? e : NEG_SLOPE * e;
    float ex = (lane < deg) ? __expf(e) : 0.0f;   // no max-subtract (bounded e)
    float s = rdlane_f(wave_sum63(ex), 63);
    float inv_s = __frcp_rn(s);

    float acc = 0.0f;
    int j = 0;
    while (true) {
        bool more = (j + 8) < deg;
        if (more) LOAD8(n, j + 8);
        FMA8(c, j);
        j += 8;
        if (!more) break;
        bool more2 = (j + 8) < deg;
        if (more2) LOAD8(c, j + 8);
        FMA8(n, j);
        j += 8;
        if (!more2) break;
    }
    acc *= inv_s;
    out[(size_t)d * D + lane] = acc + feat[(size_t)d * D + lane] + bias[lane];
}

extern "C" void kernel_launch(void* const* d_in, const int* in_sizes, int n_in,
                              void* d_out, int out_size, void* d_ws, size_t ws_size,
                              hipStream_t stream) {
    const float* feat   = (const float*)d_in[0];
    const float* W      = (const float*)d_in[1];
    const float* attn_l = (const float*)d_in[2];
    const float* attn_r = (const float*)d_in[3];
    const float* bias   = (const float*)d_in[4];
    const int*   src    = (const int*)d_in[5];
    const int*   dst    = (const int*)d_in[6];
    float* out = (float*)d_out;

    char* ws = (char*)d_ws;
    __half*   ft     = (__half*)(ws);                // [0, 12,800,000)
    unsigned* binned = (unsigned*)(ws);              // aliases ft; dead before k1_mfma
    float*    el     = (float*)(ws + 12800000);      // 400,000
    float*    er     = (float*)(ws + 13200000);      // 400,000
    int*      perm   = (int*)(ws + 13600000);        // 391*5120*4 = 8,007,680
    uint2*    rowBE  = (uint2*)(ws + 21607680);      // 800,000
    unsigned* bcnt   = (unsigned*)(ws + 22407680);   // 1,564

    hipMemsetAsync(bcnt, 0, NBKT * sizeof(unsigned), stream);
    k_bin<<<NB1, 256, 0, stream>>>(src, dst, bcnt, binned);
    k_bsort<<<NBKT, 256, 0, stream>>>(bcnt, binned, perm, rowBE);
    k1_mfma<<<(NN + 63) / 64, 256, 0, stream>>>(feat, W, attn_l, attn_r, ft, el, er);
    k_agg<<<(NN * 64 + 255) / 256, 256, 0, stream>>>(rowBE, perm, el, er,
                                                     ft, feat, bias, out);
}

// Round 13
// 93.584 us; speedup vs baseline: 4.4466x; 1.0865x over previous
//
#include <hip/hip_runtime.h>
#include <hip/hip_fp16.h>
#include <math.h>

#define NN 100000
#define NE 1600000
#define D 64
#define NEG_SLOPE 0.2f
#define NBKT 391          // ceil(NN/256) buckets of 256 dst nodes
#define NB1 196           // bin blocks
#define CHUNK 8192        // edges per bin block (%4==0)
#define BSLOT 5120        // slots per bucket (mean 4096, sd 64)
#define NTILE 1563        // ceil(NN/64) GEMM tiles

typedef __attribute__((ext_vector_type(8))) short short8;
typedef __attribute__((ext_vector_type(4))) float f32x4;

// ---------------- DPP wave reductions (VALU pipe, no LDS) ----------------
template<int CTRL>
__device__ __forceinline__ float dpp_add(float x) {
    int y = __builtin_amdgcn_update_dpp(0, __float_as_int(x), CTRL, 0xf, 0xf, true);
    return x + __int_as_float(y);
}
template<int CTRL>
__device__ __forceinline__ float dpp_max(float x) {
    int xi = __float_as_int(x);
    int y = __builtin_amdgcn_update_dpp(xi, xi, CTRL, 0xf, 0xf, false);
    return fmaxf(x, __int_as_float(y));
}
__device__ __forceinline__ float wave_sum63(float x) {
    x = dpp_add<0x111>(x); x = dpp_add<0x112>(x); x = dpp_add<0x114>(x);
    x = dpp_add<0x118>(x); x = dpp_add<0x142>(x); x = dpp_add<0x143>(x);
    return x;
}
__device__ __forceinline__ float wave_max63(float x) {
    x = dpp_max<0x111>(x); x = dpp_max<0x112>(x); x = dpp_max<0x114>(x);
    x = dpp_max<0x118>(x); x = dpp_max<0x142>(x); x = dpp_max<0x143>(x);
    return x;
}
__device__ __forceinline__ float rdlane_f(float v, int l) {
    return __int_as_float(__builtin_amdgcn_readlane(__float_as_int(v), l));
}
// RNE float->bf16 bits
__device__ __forceinline__ unsigned bf16_1(float f) {
    unsigned x = __float_as_uint(f);
    return (x + 0x7fffu + ((x >> 16) & 1u)) >> 16;
}
__device__ __forceinline__ unsigned bfpack(float a, float b) {
    return bf16_1(a) | (bf16_1(b) << 16);
}

// =====================================================================
// k_pre: blocks 0..NB1-1 bin edges; blocks NB1.. run MFMA GEMM tiles.
// The two populations share no data — pure co-scheduling, no sync.
// =====================================================================
__global__ __launch_bounds__(256) void k_pre(
    const int* __restrict__ src, const int* __restrict__ dst,
    const float* __restrict__ feat, const float* __restrict__ W,
    const float* __restrict__ attn_l, const float* __restrict__ attn_r,
    unsigned* __restrict__ bcnt, unsigned* __restrict__ binned,
    __half* __restrict__ ft, float* __restrict__ el, float* __restrict__ er)
{
    __shared__ __align__(16) char smem[16896];
    int t = threadIdx.x;

    if (blockIdx.x < NB1) {
        // ---------------- bin: histogram + self-reserve + scatter ----------
        unsigned* lh = (unsigned*)smem;
        unsigned b0 = blockIdx.x * CHUNK;
        unsigned b1 = min(b0 + CHUNK, (unsigned)NE);
        unsigned n4 = (b1 - b0) >> 2;
        for (int k = t; k < NBKT; k += 256) lh[k] = 0u;
        __syncthreads();
        const int4* d4 = (const int4*)(dst + b0);
        const int4* s4 = (const int4*)(src + b0);
        for (unsigned i = t; i < n4; i += 256) {
            int4 v = d4[i];
            atomicAdd(&lh[((unsigned)v.x) >> 8], 1u);
            atomicAdd(&lh[((unsigned)v.y) >> 8], 1u);
            atomicAdd(&lh[((unsigned)v.z) >> 8], 1u);
            atomicAdd(&lh[((unsigned)v.w) >> 8], 1u);
        }
        __syncthreads();
        for (int k = t; k < NBKT; k += 256) {
            unsigned c = lh[k];
            if (c) lh[k] = (unsigned)k * BSLOT + atomicAdd(&bcnt[k], c);
        }
        __syncthreads();
        for (unsigned i = t; i < n4; i += 256) {
            int4 dv = d4[i];
            int4 sv = s4[i];
            { unsigned d_=(unsigned)dv.x, s_=(unsigned)sv.x;
              unsigned pos=atomicAdd(&lh[d_>>8],1u); binned[pos]=(s_<<8)|(d_&255u); }
            { unsigned d_=(unsigned)dv.y, s_=(unsigned)sv.y;
              unsigned pos=atomicAdd(&lh[d_>>8],1u); binned[pos]=(s_<<8)|(d_&255u); }
            { unsigned d_=(unsigned)dv.z, s_=(unsigned)sv.z;
              unsigned pos=atomicAdd(&lh[d_>>8],1u); binned[pos]=(s_<<8)|(d_&255u); }
            { unsigned d_=(unsigned)dv.w, s_=(unsigned)sv.w;
              unsigned pos=atomicAdd(&lh[d_>>8],1u); binned[pos]=(s_<<8)|(d_&255u); }
        }
        return;
    }

    // ---------------- MFMA GEMM tile ----------------
    unsigned short* Ab = (unsigned short*)smem;            // 8192 B
    unsigned short* Bb = (unsigned short*)(smem + 8192);   // 8192 B
    float* wlS = (float*)(smem + 16384);                   // 256 B
    float* wrS = (float*)(smem + 16640);                   // 256 B
    int n0 = (int)(blockIdx.x - NB1) * 64;

    {
        int k = t >> 2, s = t & 3;
        float pl = 0.f, pr = 0.f;
        #pragma unroll
        for (int q = 0; q < 4; ++q) {
            int seg = s + q * 4;
            float4 f = *(const float4*)(W + k * 64 + seg * 4);
            float4 a = *(const float4*)(attn_l + seg * 4);
            float4 b = *(const float4*)(attn_r + seg * 4);
            pl += f.x*a.x + f.y*a.y + f.z*a.z + f.w*a.w;
            pr += f.x*b.x + f.y*b.y + f.z*b.z + f.w*b.w;
        }
        pl += __shfl_xor(pl, 1, 64); pl += __shfl_xor(pl, 2, 64);
        pr += __shfl_xor(pr, 1, 64); pr += __shfl_xor(pr, 2, 64);
        if (s == 0) { wlS[k] = pl; wrS[k] = pr; }
    }
    {
        int j = t & 63, g = t >> 6;
        unsigned m = (unsigned)((j & 7) << 4);
        #pragma unroll
        for (int i = 0; i < 8; ++i) {
            int k0 = g * 16 + i * 2;
            float w0 = W[k0 * 64 + j];
            float w1 = W[(k0 + 1) * 64 + j];
            *(unsigned*)((char*)Bb + j * 128 + (((unsigned)(k0 * 2)) ^ m)) = bfpack(w0, w1);
        }
    }
    __syncthreads();
    {
        int r = t >> 2, s = t & 3;
        int n = n0 + r;
        bool valid = n < NN;
        const float* fp = feat + (size_t)(valid ? n : (NN - 1)) * D;
        float pl = 0.f, pr = 0.f;
        unsigned m = (unsigned)((r & 7) << 4);
        #pragma unroll
        for (int q = 0; q < 4; ++q) {
            int seg = s + q * 4;
            float4 f = *(const float4*)(fp + seg * 4);
            float4 a = *(const float4*)(wlS + seg * 4);
            float4 b = *(const float4*)(wrS + seg * 4);
            pl += f.x*a.x + f.y*a.y + f.z*a.z + f.w*a.w;
            pr += f.x*b.x + f.y*b.y + f.z*b.z + f.w*b.w;
            uint2 pk;
            pk.x = bfpack(f.x, f.y);
            pk.y = bfpack(f.z, f.w);
            *(uint2*)((char*)Ab + r * 128 + (((unsigned)(seg * 8)) ^ m)) = pk;
        }
        pl += __shfl_xor(pl, 1, 64); pl += __shfl_xor(pl, 2, 64);
        pr += __shfl_xor(pr, 1, 64); pr += __shfl_xor(pr, 2, 64);
        if (s == 0 && valid) { el[n] = pl; er[n] = pr; }
    }
    __syncthreads();

    int w = t >> 6, l = t & 63;
    int lr = l & 15, lg = l >> 4;
    f32x4 acc0 = {0.f,0.f,0.f,0.f};
    f32x4 acc1 = {0.f,0.f,0.f,0.f};
    f32x4 acc2 = {0.f,0.f,0.f,0.f};
    f32x4 acc3 = {0.f,0.f,0.f,0.f};

    int jrow = w * 16 + lr;
    unsigned bm = (unsigned)((jrow & 7) << 4);
    short8 bf0 = *(const short8*)((char*)Bb + jrow * 128 + (((unsigned)(0 + lg * 16)) ^ bm));
    short8 bf1 = *(const short8*)((char*)Bb + jrow * 128 + (((unsigned)(64 + lg * 16)) ^ bm));

    #pragma unroll
    for (int rt = 0; rt < 4; ++rt) {
        int arow = rt * 16 + lr;
        unsigned am = (unsigned)((arow & 7) << 4);
        short8 a0 = *(const short8*)((char*)Ab + arow * 128 + (((unsigned)(0 + lg * 16)) ^ am));
        short8 a1 = *(const short8*)((char*)Ab + arow * 128 + (((unsigned)(64 + lg * 16)) ^ am));
        f32x4 acc = (rt == 0) ? acc0 : (rt == 1) ? acc1 : (rt == 2) ? acc2 : acc3;
        acc = __builtin_amdgcn_mfma_f32_16x16x32_bf16(a0, bf0, acc, 0, 0, 0);
        acc = __builtin_amdgcn_mfma_f32_16x16x32_bf16(a1, bf1, acc, 0, 0, 0);
        if (rt == 0) acc0 = acc; else if (rt == 1) acc1 = acc;
        else if (rt == 2) acc2 = acc; else acc3 = acc;
    }

    int col = w * 16 + lr;
    #pragma unroll
    for (int rt = 0; rt < 4; ++rt) {
        f32x4 acc = (rt == 0) ? acc0 : (rt == 1) ? acc1 : (rt == 2) ? acc2 : acc3;
        #pragma unroll
        for (int i = 0; i < 4; ++i) {
            int row = rt * 16 + lg * 4 + i;
            int nn = n0 + row;
            if (nn < NN) ft[(size_t)nn * D + col] = __float2half(acc[i]);
        }
    }
}

// ---- k_bsort: per-bucket counting sort; emits per-node (beg,end) ----
__global__ __launch_bounds__(256) void k_bsort(const unsigned* __restrict__ bcnt,
                                               const unsigned* __restrict__ binned,
                                               int* __restrict__ perm,
                                               uint2* __restrict__ rowBE) {
    __shared__ unsigned lh[256];
    __shared__ unsigned cur[256];
    __shared__ unsigned stage[BSLOT];
    int t = threadIdx.x;
    int b = blockIdx.x;
    unsigned beg = (unsigned)b * BSLOT;
    unsigned cnt = bcnt[b];
    lh[t] = 0u;
    __syncthreads();
    for (unsigned i = t; i < cnt; i += 256) {
        unsigned w = binned[beg + i];
        stage[i] = w;
        atomicAdd(&lh[w & 255u], 1u);
    }
    __syncthreads();
    for (int off = 1; off < 256; off <<= 1) {     // inclusive scan
        unsigned u = (t >= off) ? lh[t - off] : 0u;
        __syncthreads();
        lh[t] += u;
        __syncthreads();
    }
    unsigned start = (t == 0) ? 0u : lh[t - 1];
    unsigned node = ((unsigned)b << 8) + (unsigned)t;
    if (node < NN) {
        uint2 be; be.x = beg + start; be.y = beg + lh[t];
        rowBE[node] = be;
    }
    cur[t] = start;
    __syncthreads();
    for (unsigned i = t; i < cnt; i += 256) {
        unsigned w = stage[i];
        unsigned pos = atomicAdd(&cur[w & 255u], 1u);
        perm[beg + pos] = (int)(w >> 8);
    }
}

// ---- fallback: full-wave processing of one node (deg > 64) ----
__device__ __noinline__ void agg_node64(int d, int lane, unsigned beg, unsigned end,
                                        const int* __restrict__ perm_src,
                                        const float* __restrict__ el, float er_d,
                                        const __half* __restrict__ ft,
                                        const float* __restrict__ feat,
                                        const float* __restrict__ bias,
                                        float* __restrict__ out) {
    float acc = 0.0f;
    float s = 0.0f;
    float m = -INFINITY;
    for (unsigned base = beg; base < end; base += 64) {
        unsigned i = base + lane;
        float e = -INFINITY;
        if (i < end) {
            int sid2 = perm_src[i];
            float v = el[sid2] + er_d;
            e = v > 0.0f ? v : NEG_SLOPE * v;
        }
        m = fmaxf(m, rdlane_f(wave_max63(e), 63));
    }
    for (unsigned base = beg; base < end; base += 64) {
        unsigned i = base + lane;
        float exx = 0.0f;
        if (i < end) {
            int sid2 = perm_src[i];
            float v = el[sid2] + er_d;
            v = v > 0.0f ? v : NEG_SLOPE * v;
            exx = __expf(v - m);
        }
        s += rdlane_f(wave_sum63(exx), 63);
    }
    for (unsigned jj = beg; jj < end; ++jj) {
        int sj = perm_src[jj];
        float v = el[sj] + er_d;
        v = v > 0.0f ? v : NEG_SLOPE * v;
        acc = fmaf(__half2float(ft[((size_t)sj << 6) + lane]), __expf(v - m), acc);
    }
    acc /= s;
    out[(size_t)d * D + lane] = acc + feat[(size_t)d * D + lane] + bias[lane];
}

// 32-bit byte-offset gather (R10-proven form): base + (sid<<7 | lane<<1)
#define LOAD8(B, J) do { \
    unsigned _o0 = (((unsigned)__builtin_amdgcn_readlane(sid, (J) + 0)) << 7) | lb; \
    unsigned _o1 = (((unsigned)__builtin_amdgcn_readlane(sid, (J) + 1)) << 7) | lb; \
    unsigned _o2 = (((unsigned)__builtin_amdgcn_readlane(sid, (J) + 2)) << 7) | lb; \
    unsigned _o3 = (((unsigned)__builtin_amdgcn_readlane(sid, (J) + 3)) << 7) | lb; \
    unsigned _o4 = (((unsigned)__builtin_amdgcn_readlane(sid, (J) + 4)) << 7) | lb; \
    unsigned _o5 = (((unsigned)__builtin_amdgcn_readlane(sid, (J) + 5)) << 7) | lb; \
    unsigned _o6 = (((unsigned)__builtin_amdgcn_readlane(sid, (J) + 6)) << 7) | lb; \
    unsigned _o7 = (((unsigned)__builtin_amdgcn_readlane(sid, (J) + 7)) << 7) | lb; \
    B##0 = *(const __half*)(ftb + _o0); \
    B##1 = *(const __half*)(ftb + _o1); \
    B##2 = *(const __half*)(ftb + _o2); \
    B##3 = *(const __half*)(ftb + _o3); \
    B##4 = *(const __half*)(ftb + _o4); \
    B##5 = *(const __half*)(ftb + _o5); \
    B##6 = *(const __half*)(ftb + _o6); \
    B##7 = *(const __half*)(ftb + _o7); \
} while (0)

#define FMA8(B, J) do { \
    acc = fmaf(__half2float(B##0), rdlane_f(ex, (J) + 0), acc); \
    acc = fmaf(__half2float(B##1), rdlane_f(ex, (J) + 1), acc); \
    acc = fmaf(__half2float(B##2), rdlane_f(ex, (J) + 2), acc); \
    acc = fmaf(__half2float(B##3), rdlane_f(ex, (J) + 3), acc); \
    acc = fmaf(__half2float(B##4), rdlane_f(ex, (J) + 4), acc); \
    acc = fmaf(__half2float(B##5), rdlane_f(ex, (J) + 5), acc); \
    acc = fmaf(__half2float(B##6), rdlane_f(ex, (J) + 6), acc); \
    acc = fmaf(__half2float(B##7), rdlane_f(ex, (J) + 7), acc); \
} while (0)

// fused edge-softmax + aggregation, one wave per node, software-pipelined.
__global__ __launch_bounds__(256) void k_agg(const uint2* __restrict__ rowBE,
                                             const int* __restrict__ perm_src,
                                             const float* __restrict__ el,
                                             const float* __restrict__ er,
                                             const __half* __restrict__ ft,
                                             const float* __restrict__ feat,
                                             const float* __restrict__ bias,
                                             float* __restrict__ out) {
    int gid = blockIdx.x * 256 + threadIdx.x;
    int d = gid >> 6;
    int lane = gid & 63;
    if (d >= NN) return;

    uint2 be = rowBE[d];
    unsigned beg = be.x;
    int deg = (int)(be.y - be.x);
    float er_d = er[d];

    if (deg > 64) {
        agg_node64(d, lane, be.x, be.y, perm_src, el, er_d, ft, feat, bias, out);
        return;
    }
    if (deg == 0) {
        out[(size_t)d * D + lane] = feat[(size_t)d * D + lane] + bias[lane];
        return;
    }

    int sid = perm_src[beg + ((lane < deg) ? lane : 0)];
    float elv = el[sid];                      // issued early

    const char* ftb = (const char*)ft;
    unsigned lb = (unsigned)lane << 1;

    __half c0, c1, c2, c3, c4, c5, c6, c7;
    __half n0, n1, n2, n3, n4, n5, n6, n7;
    LOAD8(c, 0);                              // batch 0 in flight during softmax

    float e = elv + er_d;
    e = e > 0.0f ? e : NEG_SLOPE * e;
    float ex = (lane < deg) ? __expf(e) : 0.0f;   // no max-subtract (bounded e)
    float s = rdlane_f(wave_sum63(ex), 63);
    float inv_s = __frcp_rn(s);

    float acc = 0.0f;
    int j = 0;
    while (true) {
        bool more = (j + 8) < deg;
        if (more) LOAD8(n, j + 8);
        FMA8(c, j);
        j += 8;
        if (!more) break;
        bool more2 = (j + 8) < deg;
        if (more2) LOAD8(c, j + 8);
        FMA8(n, j);
        j += 8;
        if (!more2) break;
    }
    acc *= inv_s;
    out[(size_t)d * D + lane] = acc + feat[(size_t)d * D + lane] + bias[lane];
}

extern "C" void kernel_launch(void* const* d_in, const int* in_sizes, int n_in,
                              void* d_out, int out_size, void* d_ws, size_t ws_size,
                              hipStream_t stream) {
    const float* feat   = (const float*)d_in[0];
    const float* W      = (const float*)d_in[1];
    const float* attn_l = (const float*)d_in[2];
    const float* attn_r = (const float*)d_in[3];
    const float* bias   = (const float*)d_in[4];
    const int*   src    = (const int*)d_in[5];
    const int*   dst    = (const int*)d_in[6];
    float* out = (float*)d_out;

    char* ws = (char*)d_ws;
    __half*   ft     = (__half*)(ws);                // 12,800,000
    float*    el     = (float*)(ws + 12800000);      // 400,000
    float*    er     = (float*)(ws + 13200000);      // 400,000
    int*      perm   = (int*)(ws + 13600000);        // 8,007,680 -> 21,607,680
    uint2*    rowBE  = (uint2*)(ws + 21607680);      // 800,000 -> 22,407,680
    unsigned* bcnt   = (unsigned*)(ws + 22407680);   // 1,564 -> 22,409,244
    unsigned* binned = (unsigned*)(ws + 22409248);   // 8,007,680 -> 30,416,928

    hipMemsetAsync(bcnt, 0, NBKT * sizeof(unsigned), stream);
    k_pre<<<NB1 + NTILE, 256, 0, stream>>>(src, dst, feat, W, attn_l, attn_r,
                                           bcnt, binned, ft, el, er);
    k_bsort<<<NBKT, 256, 0, stream>>>(bcnt, binned, perm, rowBE);
    k_agg<<<(NN * 64 + 255) / 256, 256, 0, stream>>>(rowBE, perm, el, er,
                                                     ft, feat, bias, out);
}